// Round 4
// baseline (322.717 us; speedup 1.0000x reference)
//
#include <hip/hip_runtime.h>

// GAE backward scan: B=8192 rows, S=2048 steps, fp32.
// R4: one workgroup (4 waves) per row; lane owns 8 contiguous steps ->
// whole row processed in ONE parallel pass (no sequential block loop, which
// left R3 latency-bound at 28% HBM). Wave shuffle suffix-scan + tiny LDS
// cross-wave combine; 2 barriers total; ~24 live floats per lane (no spill).

static constexpr int BATCH = 8192;
static constexpr int SEQ   = 2048;
static constexpr int EPL   = 8;                  // elements per lane
static constexpr float GAMMA  = 0.999f;
static constexpr float LAMBDA = 0.95f;
static constexpr float GL     = GAMMA * LAMBDA;

__global__ __launch_bounds__(256, 4) void gae_kernel(
    const float* __restrict__ rewards,
    const float* __restrict__ values,
    const int*   __restrict__ dones,
    const int*   __restrict__ mask,
    float*       __restrict__ out)   // [2*B*S]: advantages then returns
{
    __shared__ float sA[4], sB[4], sF[4];   // per-wave composition + first masked value

    const int lane = threadIdx.x & 63;
    const int wave = threadIdx.x >> 6;
    const int row  = blockIdx.x;
    const size_t off = (size_t)row * SEQ + (size_t)threadIdx.x * EPL;

    // ---- load 8 contiguous elements per array (2x float4 each) ----
    float rr[EPL], vv[EPL];
    int   dd[EPL], mm[EPL];
    {
        const float4 r0 = *reinterpret_cast<const float4*>(rewards + off);
        const float4 r1 = *reinterpret_cast<const float4*>(rewards + off + 4);
        const float4 v0 = *reinterpret_cast<const float4*>(values  + off);
        const float4 v1 = *reinterpret_cast<const float4*>(values  + off + 4);
        const int4   d0 = *reinterpret_cast<const int4*>(dones + off);
        const int4   d1 = *reinterpret_cast<const int4*>(dones + off + 4);
        const int4   m0 = *reinterpret_cast<const int4*>(mask  + off);
        const int4   m1 = *reinterpret_cast<const int4*>(mask  + off + 4);
        rr[0]=r0.x; rr[1]=r0.y; rr[2]=r0.z; rr[3]=r0.w;
        rr[4]=r1.x; rr[5]=r1.y; rr[6]=r1.z; rr[7]=r1.w;
        vv[0]=v0.x; vv[1]=v0.y; vv[2]=v0.z; vv[3]=v0.w;
        vv[4]=v1.x; vv[5]=v1.y; vv[6]=v1.z; vv[7]=v1.w;
        dd[0]=d0.x; dd[1]=d0.y; dd[2]=d0.z; dd[3]=d0.w;
        dd[4]=d1.x; dd[5]=d1.y; dd[6]=d1.z; dd[7]=d1.w;
        mm[0]=m0.x; mm[1]=m0.y; mm[2]=m0.z; mm[3]=m0.w;
        mm[4]=m1.x; mm[5]=m1.y; mm[6]=m1.z; mm[7]=m1.w;
    }

    float a[EPL], b[EPL], vm[EPL], mr[EPL], mnd[EPL];
    #pragma unroll
    for (int e = 0; e < EPL; ++e) {
        const bool m  = (mm[e] != 0);
        const bool mn = m && (dd[e] == 0);
        vm[e]  = m ? vv[e] : 0.0f;
        mr[e]  = m ? rr[e] : 0.0f;
        mnd[e] = mn ? 1.0f : 0.0f;
        a[e]   = mn ? GL : 0.0f;
    }

    // Publish each wave's first masked value for the wave-edge nv.
    if (lane == 0) sF[wave] = vm[0];
    __syncthreads();

    float nv7 = __shfl_down(vm[0], 1, 64);
    if (lane == 63) nv7 = (wave < 3) ? sF[wave + 1] : 0.0f;

    #pragma unroll
    for (int e = 0; e < EPL; ++e) {
        const float nv = (e < EPL - 1) ? vm[e + 1] : nv7;
        b[e] = mr[e] + GAMMA * nv * mnd[e] - vm[e];
    }

    // ---- local reverse-time affine composition over this lane's 8 steps ----
    float A = a[EPL - 1], B = b[EPL - 1];
    #pragma unroll
    for (int e = EPL - 2; e >= 0; --e) {
        B = fmaf(a[e], B, b[e]);
        A = a[e] * A;
    }

    // ---- wave inclusive suffix scan (lane l -> composition over lanes [l,63]) ----
    float As = A, Bs = B;
    #pragma unroll
    for (int d = 1; d < 64; d <<= 1) {
        const float Ao = __shfl_down(As, d, 64);
        const float Bo = __shfl_down(Bs, d, 64);
        if (lane + d < 64) {
            Bs = fmaf(As, Bo, Bs);
            As = As * Ao;
        }
    }

    // ---- cross-wave combine via LDS (wave w's total = lane 0's inclusive) ----
    if (lane == 0) { sA[wave] = As; sB[wave] = Bs; }
    __syncthreads();
    // Carry entering wave w (g at its latest time) = waves 3..w+1 applied to 0.
    float C = 0.0f;
    for (int w2 = 3; w2 > wave; --w2)        // wave-uniform, <=3 iterations
        C = fmaf(sA[w2], C, sB[w2]);

    // Per-lane carry: lane l+1's inclusive suffix applied to C (identity for 63).
    float cA = __shfl_down(As, 1, 64);
    float cB = __shfl_down(Bs, 1, 64);
    if (lane == 63) { cA = 1.0f; cB = 0.0f; }
    float g = fmaf(cA, C, cB);

    // ---- apply recurrence over local 8 steps, then store ----
    float adv[EPL], ret[EPL];
    #pragma unroll
    for (int e = EPL - 1; e >= 0; --e) {
        g = fmaf(a[e], g, b[e]);
        adv[e] = g;
        ret[e] = g + vm[e];
    }

    float* ap = out + off;
    float* tp = out + (size_t)BATCH * SEQ + off;
    *reinterpret_cast<float4*>(ap)     = make_float4(adv[0], adv[1], adv[2], adv[3]);
    *reinterpret_cast<float4*>(ap + 4) = make_float4(adv[4], adv[5], adv[6], adv[7]);
    *reinterpret_cast<float4*>(tp)     = make_float4(ret[0], ret[1], ret[2], ret[3]);
    *reinterpret_cast<float4*>(tp + 4) = make_float4(ret[4], ret[5], ret[6], ret[7]);
}

extern "C" void kernel_launch(void* const* d_in, const int* in_sizes, int n_in,
                              void* d_out, int out_size, void* d_ws, size_t ws_size,
                              hipStream_t stream) {
    const float* rewards = (const float*)d_in[0];
    const float* values  = (const float*)d_in[1];
    const int*   dones   = (const int*)d_in[2];
    const int*   mask    = (const int*)d_in[3];
    float* out = (float*)d_out;

    dim3 grid(BATCH), block(256);   // one workgroup (4 waves) per row
    gae_kernel<<<grid, block, 0, stream>>>(rewards, values, dones, mask, out);
}